// Round 1
// baseline (553.260 us; speedup 1.0000x reference)
//
#include <hip/hip_runtime.h>
#include <hip/hip_bf16.h>

typedef __hip_bfloat16 bf16;
typedef short short8 __attribute__((ext_vector_type(8)));
typedef float f32x4 __attribute__((ext_vector_type(4)));

#define S_LEN 2048
#define NHEADS 16
#define NKVH 4
#define HDIM 128
#define QKVN 5120
#define SCALE_F 0.08838834764831843f
#define EPS_F 1e-6f
#define NEG_INF -1e30f

__device__ __forceinline__ void async16(const bf16* g, bf16* l) {
  __builtin_amdgcn_global_load_lds(
      (const __attribute__((address_space(1))) void*)g,
      (__attribute__((address_space(3))) void*)l, 16, 0, 0);
}

__device__ __forceinline__ f32x4 mfma_bf16(short8 a, short8 b, f32x4 c) {
  return __builtin_amdgcn_mfma_f32_16x16x32_bf16(a, b, c, 0, 0, 0);
}

__device__ __forceinline__ void store_c(float* p, float v) { *p = v; }
__device__ __forceinline__ void store_c(bf16* p, float v) { *p = __float2bfloat16(v); }

// ---------------- cast f32 -> bf16 ----------------
__global__ __launch_bounds__(256) void cast_kernel(const float* __restrict__ in,
                                                   bf16* __restrict__ out, int n) {
  int i = (blockIdx.x * 256 + threadIdx.x) * 4;
  if (i + 3 < n) {
    float4 v = *(const float4*)(in + i);
    __hip_bfloat162 p0, p1;
    p0.x = __float2bfloat16(v.x); p0.y = __float2bfloat16(v.y);
    p1.x = __float2bfloat16(v.z); p1.y = __float2bfloat16(v.w);
    *(__hip_bfloat162*)(out + i) = p0;
    *(__hip_bfloat162*)(out + i + 2) = p1;
  }
}

// ---------------- tiled transpose + cast: in (H,N) f32 -> out (N,H) bf16 ----------------
__global__ __launch_bounds__(256) void transpose_cast(const float* __restrict__ in,
                                                      bf16* __restrict__ out, int H, int N,
                                                      long inBS, long outBS) {
  __shared__ float tile[32][33];
  const float* ip = in + (long)blockIdx.z * inBS;
  bf16* op = out + (long)blockIdx.z * outBS;
  int n0 = blockIdx.x * 32, h0 = blockIdx.y * 32;
  int tx = threadIdx.x, ty = threadIdx.y;
#pragma unroll
  for (int i = 0; i < 4; i++)
    tile[ty + i * 8][tx] = ip[(long)(h0 + ty + i * 8) * N + n0 + tx];
  __syncthreads();
#pragma unroll
  for (int i = 0; i < 4; i++)
    op[(long)(n0 + ty + i * 8) * H + h0 + tx] = __float2bfloat16(tile[tx][ty + i * 8]);
}

// ---------------- bt-form bf16 GEMM (m97 structure): C[m][n] = sum_k A[m][k]*BT[n][k] ----------------
template <typename CT>
__global__ __launch_bounds__(256) void gemm_bt(const bf16* __restrict__ A,
                                               const bf16* __restrict__ BT,
                                               CT* __restrict__ C, int K, int ldc) {
  __shared__ bf16 As[128 * 32];
  __shared__ bf16 Bs[128 * 32];
  const int t = threadIdx.x;
  const int wid = t >> 6, lane = t & 63;
  const int quad = lane >> 4, l16 = lane & 15;
  const int wm = (wid & 1) * 64, wn = (wid >> 1) * 64;
  const long m0 = (long)blockIdx.x * 128;
  const long n0 = (long)blockIdx.y * 128;

  const int srow = t >> 2;
  const int scol = (t & 3) * 8;
  const bf16* Ag0 = A + (m0 + srow) * K + scol;
  const bf16* Ag1 = A + (m0 + srow + 64) * K + scol;
  const bf16* Bg0 = BT + (n0 + srow) * K + scol;
  const bf16* Bg1 = BT + (n0 + srow + 64) * K + scol;
  bf16* la0 = As + t * 8;
  bf16* la1 = As + 2048 + t * 8;
  bf16* lb0 = Bs + t * 8;
  bf16* lb1 = Bs + 2048 + t * 8;

  f32x4 acc[4][4] = {};

  for (int k0 = 0; k0 < K; k0 += 32) {
    __syncthreads();
    async16(Ag0 + k0, la0);
    async16(Ag1 + k0, la1);
    async16(Bg0 + k0, lb0);
    async16(Bg1 + k0, lb1);
    __syncthreads();
    short8 af[4], bfr[4];
#pragma unroll
    for (int i = 0; i < 4; i++) {
      af[i] = *(const short8*)(As + (wm + i * 16 + l16) * 32 + quad * 8);
      bfr[i] = *(const short8*)(Bs + (wn + i * 16 + l16) * 32 + quad * 8);
    }
#pragma unroll
    for (int mi = 0; mi < 4; mi++)
#pragma unroll
      for (int ni = 0; ni < 4; ni++)
        acc[mi][ni] = mfma_bf16(af[mi], bfr[ni], acc[mi][ni]);
  }

#pragma unroll
  for (int mi = 0; mi < 4; mi++)
#pragma unroll
    for (int ni = 0; ni < 4; ni++)
#pragma unroll
      for (int r = 0; r < 4; r++) {
        long row = m0 + wm + mi * 16 + quad * 4 + r;
        long col = n0 + wn + ni * 16 + l16;
        store_c(C + row * ldc + col, acc[mi][ni][r]);
      }
}

// ---------------- QKV post: rmsnorm + rope + cache writes ----------------
__global__ __launch_bounds__(256) void qkv_post(
    const bf16* __restrict__ qkv, const float* __restrict__ qw,
    const float* __restrict__ kw, const float* __restrict__ rcos,
    const float* __restrict__ rsin, bf16* __restrict__ Q, bf16* __restrict__ Kb,
    float* __restrict__ kcache, float* __restrict__ vcache) {
  const int bs = blockIdx.x;
  const int b = bs >> 11;
  const int s = bs & 2047;
  const int t = threadIdx.x, wid = t >> 6, lane = t & 63;
  const int d0 = lane * 2;
  const bf16* row = qkv + (long)bs * QKVN;
  float cs = 0.f, sn = 0.f;
  if (lane < 16) {
    cs = rcos[s * 16 + lane];
    sn = rsin[s * 16 + lane];
  }
  for (int seg = wid; seg < 24; seg += 4) {
    if (seg < 16) {
      int h = seg;
      __hip_bfloat162 xr = *(const __hip_bfloat162*)(row + h * 256 + d0);
      float x0 = __bfloat162float(xr.x), x1 = __bfloat162float(xr.y);
      float ss = x0 * x0 + x1 * x1;
      for (int o = 32; o; o >>= 1) ss += __shfl_xor(ss, o, 64);
      float rn = rsqrtf(ss * (1.0f / 128.0f) + EPS_F);
      float y0 = x0 * rn * (1.0f + qw[d0]);
      float y1 = x1 * rn * (1.0f + qw[d0 + 1]);
      if (lane < 16) {
        float t0 = y0 * cs - y1 * sn;
        y1 = y1 * cs + y0 * sn;
        y0 = t0;
      }
      __hip_bfloat162 o2;
      o2.x = __float2bfloat16(y0); o2.y = __float2bfloat16(y1);
      *(__hip_bfloat162*)(Q + ((long)(b * NHEADS + h) * S_LEN + s) * HDIM + d0) = o2;
    } else if (seg < 20) {
      int j = seg - 16;
      __hip_bfloat162 xr = *(const __hip_bfloat162*)(row + 4096 + j * 128 + d0);
      float x0 = __bfloat162float(xr.x), x1 = __bfloat162float(xr.y);
      float ss = x0 * x0 + x1 * x1;
      for (int o = 32; o; o >>= 1) ss += __shfl_xor(ss, o, 64);
      float rn = rsqrtf(ss * (1.0f / 128.0f) + EPS_F);
      float y0 = x0 * rn * (1.0f + kw[d0]);
      float y1 = x1 * rn * (1.0f + kw[d0 + 1]);
      if (lane < 16) {
        float t0 = y0 * cs - y1 * sn;
        y1 = y1 * cs + y0 * sn;
        y0 = t0;
      }
      long idx = ((long)(b * NKVH + j) * S_LEN + s) * HDIM + d0;
      __hip_bfloat162 o2;
      o2.x = __float2bfloat16(y0); o2.y = __float2bfloat16(y1);
      *(__hip_bfloat162*)(Kb + idx) = o2;
      float2 f2; f2.x = y0; f2.y = y1;
      *(float2*)(kcache + idx) = f2;
    } else {
      int j = seg - 20;
      __hip_bfloat162 xr = *(const __hip_bfloat162*)(row + 4608 + j * 128 + d0);
      float2 f2;
      f2.x = __bfloat162float(xr.x); f2.y = __bfloat162float(xr.y);
      *(float2*)(vcache + ((long)(b * NKVH + j) * S_LEN + s) * HDIM + d0) = f2;
    }
  }
}

// ---------------- flash attention (causal, GQA) + fused sigmoid gate ----------------
__global__ __launch_bounds__(256, 2) void flash_attn(
    const bf16* __restrict__ Q, const bf16* __restrict__ Kb,
    const bf16* __restrict__ VT, const bf16* __restrict__ qkv,
    bf16* __restrict__ Aout) {
  __shared__ bf16 Ks[128 * 128];   // K tile; reused as P after a barrier
  __shared__ bf16 VTs[128 * 128];  // V^T tile (d, key)
  const int qt = blockIdx.x, h = blockIdx.y, b = blockIdx.z;
  const int kvh = h >> 2;
  const int t = threadIdx.x, wid = t >> 6, lane = t & 63;
  const int quad = lane >> 4, l16 = lane & 15;
  const int qm0 = qt * 128;

  const bf16* Qb = Q + ((long)(b * NHEADS + h) * S_LEN + qm0) * HDIM;
  short8 qf[2][4];
#pragma unroll
  for (int mi = 0; mi < 2; mi++)
#pragma unroll
    for (int kc = 0; kc < 4; kc++)
      qf[mi][kc] = *(const short8*)(Qb + (wid * 32 + mi * 16 + l16) * HDIM + kc * 32 + quad * 8);

  f32x4 oacc[2][8] = {};
  float mrun[2][4], lrun[2][4];
#pragma unroll
  for (int mi = 0; mi < 2; mi++)
#pragma unroll
    for (int r = 0; r < 4; r++) {
      mrun[mi][r] = NEG_INF;
      lrun[mi][r] = 0.f;
    }

  const bf16* Kbase = Kb + (long)(b * NKVH + kvh) * S_LEN * HDIM;
  const bf16* VTbase = VT + (long)(b * NKVH + kvh) * HDIM * S_LEN;

  for (int kt = 0; kt <= qt; kt++) {
    const int kn0 = kt * 128;
    __syncthreads();
#pragma unroll
    for (int i = 0; i < 8; i++) {
      int ci = i * 256 + t;
      int kr = ci >> 4, kc8 = (ci & 15) * 8;
      async16(Kbase + (long)(kn0 + kr) * HDIM + kc8, Ks + ci * 8);
      async16(VTbase + (long)kr * S_LEN + kn0 + kc8, VTs + ci * 8);
    }
    __syncthreads();

    // S = Q @ K^T
    f32x4 sacc[2][8] = {};
#pragma unroll
    for (int kc = 0; kc < 4; kc++) {
      short8 bfr[8];
#pragma unroll
      for (int ni = 0; ni < 8; ni++)
        bfr[ni] = *(const short8*)(Ks + (ni * 16 + l16) * 128 + kc * 32 + quad * 8);
#pragma unroll
      for (int ni = 0; ni < 8; ni++)
#pragma unroll
        for (int mi = 0; mi < 2; mi++)
          sacc[mi][ni] = mfma_bf16(qf[mi][kc], bfr[ni], sacc[mi][ni]);
    }

    // online softmax (each wave owns rows wid*32 .. wid*32+31 exclusively)
    const bool diag = (kt == qt);
#pragma unroll
    for (int mi = 0; mi < 2; mi++)
#pragma unroll
      for (int r = 0; r < 4; r++) {
        const int rloc = wid * 32 + mi * 16 + quad * 4 + r;
        float mx = NEG_INF;
#pragma unroll
        for (int ni = 0; ni < 8; ni++) {
          float v = sacc[mi][ni][r] * SCALE_F;
          if (diag && (ni * 16 + l16) > rloc) v = NEG_INF;
          sacc[mi][ni][r] = v;
          mx = fmaxf(mx, v);
        }
        for (int o = 1; o < 16; o <<= 1) mx = fmaxf(mx, __shfl_xor(mx, o, 64));
        const float mnew = fmaxf(mrun[mi][r], mx);
        const float alpha = __expf(mrun[mi][r] - mnew);
        float rsum = 0.f;
#pragma unroll
        for (int ni = 0; ni < 8; ni++) {
          float p = __expf(sacc[mi][ni][r] - mnew);
          sacc[mi][ni][r] = p;
          rsum += p;
        }
        for (int o = 1; o < 16; o <<= 1) rsum += __shfl_xor(rsum, o, 64);
        lrun[mi][r] = lrun[mi][r] * alpha + rsum;
        mrun[mi][r] = mnew;
#pragma unroll
        for (int ni = 0; ni < 8; ni++) oacc[mi][ni][r] = oacc[mi][ni][r] * alpha;
      }

    __syncthreads();  // all waves done reading Ks -> safe to overwrite with P
    bf16* Ps = Ks + wid * 32 * 128;
#pragma unroll
    for (int mi = 0; mi < 2; mi++)
#pragma unroll
      for (int ni = 0; ni < 8; ni++)
#pragma unroll
        for (int r = 0; r < 4; r++)
          Ps[(mi * 16 + quad * 4 + r) * 128 + ni * 16 + l16] =
              __float2bfloat16(sacc[mi][ni][r]);
    __syncthreads();

    // O += P @ V   (B-operand from V^T tile)
#pragma unroll
    for (int kc = 0; kc < 4; kc++) {
      short8 pf[2];
#pragma unroll
      for (int mi = 0; mi < 2; mi++)
        pf[mi] = *(const short8*)(Ps + (mi * 16 + l16) * 128 + kc * 32 + quad * 8);
#pragma unroll
      for (int ni = 0; ni < 8; ni++) {
        short8 vf = *(const short8*)(VTs + (ni * 16 + l16) * 128 + kc * 32 + quad * 8);
#pragma unroll
        for (int mi = 0; mi < 2; mi++)
          oacc[mi][ni] = mfma_bf16(pf[mi], vf, oacc[mi][ni]);
      }
    }
  }

  // epilogue: normalize, apply sigmoid gate, write bf16
#pragma unroll
  for (int mi = 0; mi < 2; mi++)
#pragma unroll
    for (int r = 0; r < 4; r++) {
      const int rloc = wid * 32 + mi * 16 + quad * 4 + r;
      const long srow = qm0 + rloc;
      const float inv = 1.0f / lrun[mi][r];
      const bf16* grow = qkv + ((long)b * S_LEN + srow) * QKVN + h * 256 + 128;
      bf16* arow = Aout + ((long)b * S_LEN + srow) * 2048 + h * 128;
#pragma unroll
      for (int ni = 0; ni < 8; ni++) {
        const int d = ni * 16 + l16;
        float g = __bfloat162float(grow[d]);
        float sg = 1.0f / (1.0f + __expf(-g));
        arow[d] = __float2bfloat16(oacc[mi][ni][r] * inv * sg);
      }
    }
}

extern "C" void kernel_launch(void* const* d_in, const int* in_sizes, int n_in,
                              void* d_out, int out_size, void* d_ws, size_t ws_size,
                              hipStream_t stream) {
  const float* hs = (const float*)d_in[0];
  const float* wq = (const float*)d_in[1];
  const float* wk = (const float*)d_in[2];
  const float* wv = (const float*)d_in[3];
  const float* wo = (const float*)d_in[4];
  const float* qnw = (const float*)d_in[5];
  const float* knw = (const float*)d_in[6];
  const float* rcos = (const float*)d_in[7];
  const float* rsin = (const float*)d_in[8];

  float* out = (float*)d_out;                 // (2,2048,2048)
  float* kcache = out + 8388608;              // (2,4,2048,128)
  float* vcache = out + 10485760;             // (2,4,2048,128)

  char* ws = (char*)d_ws;
  bf16* Xb    = (bf16*)(ws);                  // (4096,2048)
  bf16* WqkvT = (bf16*)(ws + 16777216L);      // (5120,2048)
  bf16* WoT   = (bf16*)(ws + 37748736L);      // (2048,2048)
  bf16* QKV   = (bf16*)(ws + 46137344L);      // (4096,5120)
  bf16* Qb    = (bf16*)(ws + 88080384L);      // (2,16,2048,128)
  bf16* Kbq   = (bf16*)(ws + 104857600L);     // (2,4,2048,128)
  bf16* VTb   = (bf16*)(ws + 109051904L);     // (2,4,128,2048)
  bf16* Aout  = (bf16*)(ws + 113246208L);     // (4096,2048)

  cast_kernel<<<8192, 256, 0, stream>>>(hs, Xb, 8388608);
  transpose_cast<<<dim3(128, 64, 1), dim3(32, 8), 0, stream>>>(wq, WqkvT, 2048, 4096, 0, 0);
  transpose_cast<<<dim3(16, 64, 1), dim3(32, 8), 0, stream>>>(wk, WqkvT + 4096L * 2048, 2048, 512, 0, 0);
  transpose_cast<<<dim3(16, 64, 1), dim3(32, 8), 0, stream>>>(wv, WqkvT + 4608L * 2048, 2048, 512, 0, 0);
  transpose_cast<<<dim3(64, 64, 1), dim3(32, 8), 0, stream>>>(wo, WoT, 2048, 2048, 0, 0);

  gemm_bt<bf16><<<dim3(32, 40), 256, 0, stream>>>(Xb, WqkvT, QKV, 2048, 5120);

  qkv_post<<<4096, 256, 0, stream>>>(QKV, qnw, knw, rcos, rsin, Qb, Kbq, kcache, vcache);

  // V^T (per (b,kv): (2048,128) f32 -> (128,2048) bf16)
  transpose_cast<<<dim3(4, 64, 8), dim3(32, 8), 0, stream>>>(vcache, VTb, 2048, 128,
                                                             2048L * 128, 2048L * 128);

  flash_attn<<<dim3(16, 16, 2), 256, 0, stream>>>(Qb, Kbq, VTb, QKV, Aout);

  gemm_bt<float><<<dim3(32, 16), 256, 0, stream>>>(Aout, WoT, out, 2048, 2048);
}